// Round 1
// baseline (258.625 us; speedup 1.0000x reference)
//
#include <hip/hip_runtime.h>
#include <math.h>

// Problem constants (fixed by setup_inputs()):
//   B=16 batches, N=4096 shape_query pts, P=1024 prior pts, M=4096 model pts,
//   H=64 hypotheses. Reconstructed = concat(shape_query, prior) -> 5120 pts.
#define BATCH   16
#define NQ      4096
#define NPRIOR  1024
#define NMODEL  4096
#define NHYP    64

// Zero the two accumulator slots (d_out[2], d_out[3]) each launch.
// d_out is poisoned once before timing and never re-poisoned, so we must
// re-init every call for determinism.
__global__ void init_out(float* out) {
    if (threadIdx.x == 0) { out[2] = 0.0f; out[3] = 0.0f; }
}

// Scan `cnt` reference points (cnt % 8 == 0), updating running min squared
// distance. Loop index is wave-uniform -> loads should scalarize (s_load).
__device__ __forceinline__ void scan_refs(const float* __restrict__ r, int cnt,
                                          float px, float py, float pz,
                                          float& minv) {
    for (int m = 0; m < cnt; m += 8) {
#pragma unroll
        for (int u = 0; u < 8; ++u) {
            float mx = r[(m + u) * 3 + 0];
            float my = r[(m + u) * 3 + 1];
            float mz = r[(m + u) * 3 + 2];
            float dx = px - mx;
            float dy = py - my;
            float dz = pz - mz;
            float d  = fmaf(dz, dz, fmaf(dy, dy, dx * dx));
            minv = fminf(minv, d);
        }
    }
}

// One wave per block. Each lane owns one query point (from segment qa, or qb
// for indices >= na), scans all reference points (segments ra[ma], rb[mb]),
// takes the min squared distance, wave-reduces the sum, one atomicAdd/block.
__global__ __launch_bounds__(64) void chamfer_sum(
    const float* __restrict__ qa, int na,
    const float* __restrict__ qb, int nb,
    const float* __restrict__ ra, int ma,
    const float* __restrict__ rb, int mb,
    float* __restrict__ accum) {
    const int b = blockIdx.y;
    const int n = blockIdx.x * 64 + threadIdx.x;

    float px, py, pz;
    if (n < na) {
        const float* p = qa + ((size_t)b * na + n) * 3;
        px = p[0]; py = p[1]; pz = p[2];
    } else {
        const float* p = qb + ((size_t)b * nb + (n - na)) * 3;
        px = p[0]; py = p[1]; pz = p[2];
    }

    float minv = 3.0e38f;
    scan_refs(ra + (size_t)b * ma * 3, ma, px, py, pz, minv);
    if (mb > 0) {
        scan_refs(rb + (size_t)b * mb * 3, mb, px, py, pz, minv);
    }

    // Wave-wide sum of the per-lane min distances.
    float s = minv;
#pragma unroll
    for (int off = 32; off > 0; off >>= 1) {
        s += __shfl_xor(s, off, 64);
    }
    if (threadIdx.x == 0) {
        atomicAdd(accum, s);
    }
}

// Single block (1 wave). Lanes 0..15 compute per-batch log-softmax term;
// reduce; lane 0 reads the chamfer accumulators and writes all 5 outputs.
__global__ __launch_bounds__(64) void finalize_kernel(
    const float* __restrict__ logits, float* __restrict__ out) {
    const int lane = threadIdx.x;
    float pose_part = 0.0f;
    if (lane < BATCH) {
        const float* L = logits + lane * NHYP;
        float mx = L[0];
#pragma unroll 8
        for (int j = 1; j < NHYP; ++j) mx = fmaxf(mx, L[j]);
        float s = 0.0f;
#pragma unroll 8
        for (int j = 0; j < NHYP; ++j) s += expf(L[j] - mx);
        float lse = mx + logf(s);
        pose_part = L[0] - lse;  // log_prob[b, 0]
    }
    // Sum lanes 0..15 into lane 0 (xor offsets stay within the 16-lane group).
#pragma unroll
    for (int off = 8; off > 0; off >>= 1) {
        pose_part += __shfl_xor(pose_part, off, 64);
    }
    if (lane == 0) {
        float sum1 = out[2];
        float sum2 = out[3];
        float mean1 = sum1 / (float)(BATCH * (NQ + NPRIOR));
        float mean2 = sum2 / (float)(BATCH * NMODEL);
        float shape_loss = mean1 + mean2;
        float pose_loss = -pose_part / (float)BATCH;
        float loss = 0.4f * pose_loss + 0.4f * shape_loss +
                     0.1f * shape_loss + 0.1f * shape_loss;
        out[0] = loss;
        out[1] = pose_loss;
        out[2] = shape_loss;
        out[3] = shape_loss;  // sdf_loss
        out[4] = shape_loss;  // caption_loss
    }
}

extern "C" void kernel_launch(void* const* d_in, const int* in_sizes, int n_in,
                              void* d_out, int out_size, void* d_ws, size_t ws_size,
                              hipStream_t stream) {
    const float* shape_query = (const float*)d_in[0];  // (16,4096,3)
    const float* logits      = (const float*)d_in[1];  // (16,64)
    // d_in[2], d_in[3] (captions, int) and d_in[4] (sdf_pred) are unused.
    const float* prior       = (const float*)d_in[5];  // (16,1024,3)
    const float* model       = (const float*)d_in[6];  // (16,4096,3)
    float* out = (float*)d_out;

    hipLaunchKernelGGL(init_out, dim3(1), dim3(64), 0, stream, out);

    // dist1: query = reconstructed (5120 pts), refs = model (4096 pts)
    hipLaunchKernelGGL(chamfer_sum,
                       dim3((NQ + NPRIOR) / 64, BATCH), dim3(64), 0, stream,
                       shape_query, NQ, prior, NPRIOR,
                       model, NMODEL, (const float*)nullptr, 0,
                       out + 2);

    // dist2: query = model (4096 pts), refs = reconstructed (5120 pts)
    hipLaunchKernelGGL(chamfer_sum,
                       dim3(NMODEL / 64, BATCH), dim3(64), 0, stream,
                       model, NMODEL, (const float*)nullptr, 0,
                       shape_query, NQ, prior, NPRIOR,
                       out + 3);

    hipLaunchKernelGGL(finalize_kernel, dim3(1), dim3(64), 0, stream,
                       logits, out);
}

// Round 2
// 93.941 us; speedup vs baseline: 2.7531x; 2.7531x over previous
//
#include <hip/hip_runtime.h>
#include <math.h>

// Problem constants (fixed by setup_inputs()):
#define BATCH   16
#define NQ      4096      // shape_query pts per batch
#define NPRIOR  1024      // prior pts per batch
#define NREC    5120      // reconstructed = concat(shape_query, prior)
#define NMODEL  4096      // model pts per batch
#define NHYP    64

// Fused-chamfer decomposition:
#define SLICES  8                   // ref-dimension split per query tile
#define BLK     128                 // 2 waves per block
#define QPL     8                   // query points per lane
#define QTILE   (BLK*QPL)           // 1024 queries per block (divides 5120 & 4096)
#define QT1     (NREC/QTILE)        // 5 query tiles (dir1, per batch)
#define QT2     (NMODEL/QTILE)      // 4 query tiles (dir2, per batch)
#define RS1     (NMODEL/SLICES)     // 512 refs per slice (dir1)
#define RS2     (NREC/SLICES)       // 640 refs per slice (dir2)
#define NQD1    (BATCH*NREC)        // 81920 dir1 queries
#define NQD2    (BATCH*NMODEL)      // 65536 dir2 queries
#define WS_WORDS (NQD1+NQD2)        // 147456 uint mins
#define WS_BYTES ((size_t)WS_WORDS*4)

// Order-preserving float<->uint map (handles negatives from fp cancellation)
// so atomicMin on uint == min on float.
__device__ __forceinline__ unsigned f2ord(float f) {
    unsigned b = __float_as_uint(f);
    return (b & 0x80000000u) ? ~b : (b | 0x80000000u);
}
__device__ __forceinline__ float ord2f(unsigned u) {
    return (u & 0x80000000u) ? __uint_as_float(u & 0x7fffffffu)
                             : __uint_as_float(~u);
}

// ---------------- fused path (needs d_ws >= WS_BYTES) ----------------

__global__ __launch_bounds__(256) void init_ws(unsigned int* __restrict__ ws,
                                               float* __restrict__ out) {
    int i = blockIdx.x * 256 + threadIdx.x;
    if (i == 0) { out[2] = 0.0f; out[3] = 0.0f; }
    for (; i < WS_WORDS; i += gridDim.x * 256) ws[i] = 0xFFFFFFFFu;
}

__global__ __launch_bounds__(BLK) void chamfer_main(
    const float* __restrict__ shape_query,
    const float* __restrict__ prior,
    const float* __restrict__ model,
    unsigned int* __restrict__ ws) {
    __shared__ float4 refs[RS2];  // 640 * 16B = 10 KB

    int id = blockIdx.x;
    int dir, b, qt, s;
    if (id < BATCH * QT1 * SLICES) {
        dir = 0;
        b = id / (QT1 * SLICES);
        int r = id % (QT1 * SLICES);
        qt = r / SLICES; s = r % SLICES;
    } else {
        int j = id - BATCH * QT1 * SLICES;
        dir = 1;
        b = j / (QT2 * SLICES);
        int r = j % (QT2 * SLICES);
        qt = r / SLICES; s = r % SLICES;
    }

    const int tid = threadIdx.x;
    const int rcount = (dir == 0) ? RS1 : RS2;
    const int rbase  = s * rcount;

    // Stage this block's ref slice into LDS as (x,y,z,||r||^2).
    for (int i = tid; i < rcount; i += BLK) {
        int j = rbase + i;
        const float* p;
        if (dir == 0) {
            p = model + ((size_t)b * NMODEL + j) * 3;
        } else {
            p = (j < NQ) ? shape_query + ((size_t)b * NQ + j) * 3
                         : prior + ((size_t)b * NPRIOR + (j - NQ)) * 3;
        }
        float x = p[0], y = p[1], z = p[2];
        float nb = fmaf(z, z, fmaf(y, y, x * x));
        refs[i] = make_float4(x, y, z, nb);
    }

    // Load 8 query points per lane; fold the -2 into the coords.
    float qx2[QPL], qy2[QPL], qz2[QPL], na[QPL], mn[QPL];
    const int nq_per_batch = (dir == 0) ? NREC : NMODEL;
#pragma unroll
    for (int q = 0; q < QPL; ++q) {
        int j = qt * QTILE + q * BLK + tid;  // index within batch
        const float* p;
        if (dir == 0) {
            p = (j < NQ) ? shape_query + ((size_t)b * NQ + j) * 3
                         : prior + ((size_t)b * NPRIOR + (j - NQ)) * 3;
        } else {
            p = model + ((size_t)b * NMODEL + j) * 3;
        }
        float x = p[0], y = p[1], z = p[2];
        na[q]  = fmaf(z, z, fmaf(y, y, x * x));
        qx2[q] = -2.0f * x; qy2[q] = -2.0f * y; qz2[q] = -2.0f * z;
        mn[q]  = 3.0e38f;
    }

    __syncthreads();

    // Inner loop: 1 uniform ds_read_b128 + 4 VALU ops per (ref, query).
#pragma unroll 2
    for (int m = 0; m < rcount; ++m) {
        float4 r = refs[m];
#pragma unroll
        for (int q = 0; q < QPL; ++q) {
            float t = fmaf(qx2[q], r.x, r.w);
            t = fmaf(qy2[q], r.y, t);
            t = fmaf(qz2[q], r.z, t);
            mn[q] = fminf(mn[q], t);
        }
    }

    unsigned int* wsd = ws + ((dir == 0) ? 0 : NQD1);
    const int qgbase = b * nq_per_batch + qt * QTILE;
#pragma unroll
    for (int q = 0; q < QPL; ++q) {
        float v = mn[q] + na[q];  // actual min squared distance candidate
        atomicMin(&wsd[qgbase + q * BLK + tid], f2ord(v));
    }
}

__global__ __launch_bounds__(256) void reduce_sums(
    const unsigned int* __restrict__ ws, float* __restrict__ out) {
    float s1 = 0.0f, s2 = 0.0f;
    for (int i = blockIdx.x * 256 + threadIdx.x; i < WS_WORDS;
         i += gridDim.x * 256) {
        float v = ord2f(ws[i]);
        if (i < NQD1) s1 += v; else s2 += v;
    }
#pragma unroll
    for (int off = 32; off > 0; off >>= 1) {
        s1 += __shfl_xor(s1, off, 64);
        s2 += __shfl_xor(s2, off, 64);
    }
    __shared__ float a1[4], a2[4];
    int w = threadIdx.x >> 6;
    if ((threadIdx.x & 63) == 0) { a1[w] = s1; a2[w] = s2; }
    __syncthreads();
    if (threadIdx.x == 0) {
        atomicAdd(&out[2], a1[0] + a1[1] + a1[2] + a1[3]);
        atomicAdd(&out[3], a2[0] + a2[1] + a2[2] + a2[3]);
    }
}

// ---------------- fallback path (round-1, no d_ws) ----------------

__global__ void init_out(float* out) {
    if (threadIdx.x == 0) { out[2] = 0.0f; out[3] = 0.0f; }
}

__device__ __forceinline__ void scan_refs(const float* __restrict__ r, int cnt,
                                          float px, float py, float pz,
                                          float& minv) {
    for (int m = 0; m < cnt; m += 8) {
#pragma unroll
        for (int u = 0; u < 8; ++u) {
            float mx = r[(m + u) * 3 + 0];
            float my = r[(m + u) * 3 + 1];
            float mz = r[(m + u) * 3 + 2];
            float dx = px - mx, dy = py - my, dz = pz - mz;
            float d = fmaf(dz, dz, fmaf(dy, dy, dx * dx));
            minv = fminf(minv, d);
        }
    }
}

__global__ __launch_bounds__(64) void chamfer_sum(
    const float* __restrict__ qa, int na_, const float* __restrict__ qb, int nb_,
    const float* __restrict__ ra, int ma, const float* __restrict__ rb, int mb,
    float* __restrict__ accum) {
    const int b = blockIdx.y;
    const int n = blockIdx.x * 64 + threadIdx.x;
    float px, py, pz;
    if (n < na_) {
        const float* p = qa + ((size_t)b * na_ + n) * 3;
        px = p[0]; py = p[1]; pz = p[2];
    } else {
        const float* p = qb + ((size_t)b * nb_ + (n - na_)) * 3;
        px = p[0]; py = p[1]; pz = p[2];
    }
    float minv = 3.0e38f;
    scan_refs(ra + (size_t)b * ma * 3, ma, px, py, pz, minv);
    if (mb > 0) scan_refs(rb + (size_t)b * mb * 3, mb, px, py, pz, minv);
    float s = minv;
#pragma unroll
    for (int off = 32; off > 0; off >>= 1) s += __shfl_xor(s, off, 64);
    if (threadIdx.x == 0) atomicAdd(accum, s);
}

// ---------------- finalize (shared by both paths) ----------------

__global__ __launch_bounds__(64) void finalize_kernel(
    const float* __restrict__ logits, float* __restrict__ out) {
    const int lane = threadIdx.x;
    float pose_part = 0.0f;
    if (lane < BATCH) {
        const float* L = logits + lane * NHYP;
        float mx = L[0];
#pragma unroll 8
        for (int j = 1; j < NHYP; ++j) mx = fmaxf(mx, L[j]);
        float s = 0.0f;
#pragma unroll 8
        for (int j = 0; j < NHYP; ++j) s += expf(L[j] - mx);
        pose_part = L[0] - (mx + logf(s));  // log_prob[b, 0]
    }
#pragma unroll
    for (int off = 8; off > 0; off >>= 1) pose_part += __shfl_xor(pose_part, off, 64);
    if (lane == 0) {
        float mean1 = out[2] / (float)NQD1;
        float mean2 = out[3] / (float)NQD2;
        float shape_loss = mean1 + mean2;
        float pose_loss = -pose_part / (float)BATCH;
        float loss = 0.4f * pose_loss + 0.6f * shape_loss;
        out[0] = loss;
        out[1] = pose_loss;
        out[2] = shape_loss;
        out[3] = shape_loss;  // sdf_loss
        out[4] = shape_loss;  // caption_loss
    }
}

extern "C" void kernel_launch(void* const* d_in, const int* in_sizes, int n_in,
                              void* d_out, int out_size, void* d_ws, size_t ws_size,
                              hipStream_t stream) {
    const float* shape_query = (const float*)d_in[0];  // (16,4096,3)
    const float* logits      = (const float*)d_in[1];  // (16,64)
    const float* prior       = (const float*)d_in[5];  // (16,1024,3)
    const float* model       = (const float*)d_in[6];  // (16,4096,3)
    float* out = (float*)d_out;

    if (ws_size >= WS_BYTES) {
        unsigned int* ws = (unsigned int*)d_ws;
        hipLaunchKernelGGL(init_ws, dim3(288), dim3(256), 0, stream, ws, out);
        const int nblocks = BATCH * QT1 * SLICES + BATCH * QT2 * SLICES;  // 1152
        hipLaunchKernelGGL(chamfer_main, dim3(nblocks), dim3(BLK), 0, stream,
                           shape_query, prior, model, ws);
        hipLaunchKernelGGL(reduce_sums, dim3(128), dim3(256), 0, stream, ws, out);
    } else {
        hipLaunchKernelGGL(init_out, dim3(1), dim3(64), 0, stream, out);
        hipLaunchKernelGGL(chamfer_sum,
                           dim3(NREC / 64, BATCH), dim3(64), 0, stream,
                           shape_query, NQ, prior, NPRIOR,
                           model, NMODEL, (const float*)nullptr, 0, out + 2);
        hipLaunchKernelGGL(chamfer_sum,
                           dim3(NMODEL / 64, BATCH), dim3(64), 0, stream,
                           model, NMODEL, (const float*)nullptr, 0,
                           shape_query, NQ, prior, NPRIOR, out + 3);
    }
    hipLaunchKernelGGL(finalize_kernel, dim3(1), dim3(64), 0, stream, logits, out);
}

// Round 3
// 78.759 us; speedup vs baseline: 3.2838x; 1.1928x over previous
//
#include <hip/hip_runtime.h>
#include <math.h>

// Problem constants (fixed by setup_inputs()):
#define BATCH   16
#define NQ      4096      // shape_query pts per batch
#define NPRIOR  1024      // prior pts per batch
#define NREC    5120      // reconstructed = concat(shape_query, prior)
#define NMODEL  4096      // model pts per batch
#define NHYP    64

// Fused-chamfer decomposition:
#define SLICES  16                  // ref-dimension split per query tile
#define BLK     128                 // 2 waves per block
#define QPL     8                   // query points per lane
#define QTILE   (BLK*QPL)           // 1024 queries per block (divides 5120 & 4096)
#define QT1     (NREC/QTILE)        // 5 query tiles (dir1, per batch)
#define QT2     (NMODEL/QTILE)      // 4 query tiles (dir2, per batch)
#define RS1     (NMODEL/SLICES)     // 256 refs per slice (dir1)
#define RS2     (NREC/SLICES)       // 320 refs per slice (dir2)
#define NQD1    (BATCH*NREC)        // 81920 dir1 queries
#define NQD2    (BATCH*NMODEL)      // 65536 dir2 queries
#define WS_WORDS (NQD1+NQD2)        // 147456 uint mins
#define WS_BYTES ((size_t)WS_WORDS*4)

// Order-preserving float<->uint map so atomicMin on uint == min on float.
__device__ __forceinline__ unsigned f2ord(float f) {
    unsigned b = __float_as_uint(f);
    return (b & 0x80000000u) ? ~b : (b | 0x80000000u);
}
__device__ __forceinline__ float ord2f(unsigned u) {
    return (u & 0x80000000u) ? __uint_as_float(u & 0x7fffffffu)
                             : __uint_as_float(~u);
}

// Single-instruction 3-input min (VOP3; no literal operands used).
__device__ __forceinline__ float min3f(float a, float b, float c) {
    float d;
    asm("v_min3_f32 %0, %1, %2, %3" : "=v"(d) : "v"(a), "v"(b), "v"(c));
    return d;
}

// ---------------- fused path (needs d_ws >= WS_BYTES) ----------------

__global__ __launch_bounds__(256) void init_ws(unsigned int* __restrict__ ws,
                                               float* __restrict__ out) {
    int i = blockIdx.x * 256 + threadIdx.x;
    if (i == 0) { out[2] = 0.0f; out[3] = 0.0f; }
    if (i < WS_WORDS) ws[i] = 0xFFFFFFFFu;
}

__global__ __launch_bounds__(BLK) void chamfer_main(
    const float* __restrict__ shape_query,
    const float* __restrict__ prior,
    const float* __restrict__ model,
    unsigned int* __restrict__ ws) {
    __shared__ float4 refs[RS2];  // 320 * 16B = 5 KB

    int id = blockIdx.x;
    int dir, b, qt, s;
    if (id < BATCH * QT1 * SLICES) {
        dir = 0;
        b = id / (QT1 * SLICES);
        int r = id % (QT1 * SLICES);
        qt = r / SLICES; s = r % SLICES;
    } else {
        int j = id - BATCH * QT1 * SLICES;
        dir = 1;
        b = j / (QT2 * SLICES);
        int r = j % (QT2 * SLICES);
        qt = r / SLICES; s = r % SLICES;
    }

    const int tid = threadIdx.x;
    const int rcount = (dir == 0) ? RS1 : RS2;
    const int rbase  = s * rcount;

    // Stage this block's ref slice into LDS as (x,y,z,||r||^2).
    for (int i = tid; i < rcount; i += BLK) {
        int j = rbase + i;
        const float* p;
        if (dir == 0) {
            p = model + ((size_t)b * NMODEL + j) * 3;
        } else {
            p = (j < NQ) ? shape_query + ((size_t)b * NQ + j) * 3
                         : prior + ((size_t)b * NPRIOR + (j - NQ)) * 3;
        }
        float x = p[0], y = p[1], z = p[2];
        float nb = fmaf(z, z, fmaf(y, y, x * x));
        refs[i] = make_float4(x, y, z, nb);
    }

    // Load 8 query points per lane; fold the -2 into the coords.
    // ||q||^2 is recomputed after the loop from qx2 (saves live registers).
    float qx2[QPL], qy2[QPL], qz2[QPL], mn[QPL];
    const int nq_per_batch = (dir == 0) ? NREC : NMODEL;
#pragma unroll
    for (int q = 0; q < QPL; ++q) {
        int j = qt * QTILE + q * BLK + tid;  // index within batch
        const float* p;
        if (dir == 0) {
            p = (j < NQ) ? shape_query + ((size_t)b * NQ + j) * 3
                         : prior + ((size_t)b * NPRIOR + (j - NQ)) * 3;
        } else {
            p = model + ((size_t)b * NMODEL + j) * 3;
        }
        qx2[q] = -2.0f * p[0]; qy2[q] = -2.0f * p[1]; qz2[q] = -2.0f * p[2];
        mn[q]  = 3.0e38f;
    }

    __syncthreads();

    // Inner loop: 8 refs per iteration. 8 independent uniform ds_read_b128
    // issued together (one wait), then 8q x (24 fma + 4 min3) = 3.5 VALU
    // ops per (ref, query) pair.
#pragma unroll 1
    for (int m = 0; m < rcount; m += 8) {
        float4 r0 = refs[m + 0], r1 = refs[m + 1];
        float4 r2 = refs[m + 2], r3 = refs[m + 3];
        float4 r4 = refs[m + 4], r5 = refs[m + 5];
        float4 r6 = refs[m + 6], r7 = refs[m + 7];
#pragma unroll
        for (int q = 0; q < QPL; ++q) {
            float x = qx2[q], y = qy2[q], z = qz2[q];
            float d0 = fmaf(z, r0.z, fmaf(y, r0.y, fmaf(x, r0.x, r0.w)));
            float d1 = fmaf(z, r1.z, fmaf(y, r1.y, fmaf(x, r1.x, r1.w)));
            float d2 = fmaf(z, r2.z, fmaf(y, r2.y, fmaf(x, r2.x, r2.w)));
            float d3 = fmaf(z, r3.z, fmaf(y, r3.y, fmaf(x, r3.x, r3.w)));
            float d4 = fmaf(z, r4.z, fmaf(y, r4.y, fmaf(x, r4.x, r4.w)));
            float d5 = fmaf(z, r5.z, fmaf(y, r5.y, fmaf(x, r5.x, r5.w)));
            float d6 = fmaf(z, r6.z, fmaf(y, r6.y, fmaf(x, r6.x, r6.w)));
            float d7 = fmaf(z, r7.z, fmaf(y, r7.y, fmaf(x, r7.x, r7.w)));
            float t0 = min3f(d0, d1, d2);
            float t1 = min3f(d3, d4, d5);
            float t2 = min3f(t0, t1, d6);
            mn[q] = min3f(mn[q], t2, d7);
        }
    }

    unsigned int* wsd = ws + ((dir == 0) ? 0 : NQD1);
    const int qgbase = b * nq_per_batch + qt * QTILE;
#pragma unroll
    for (int q = 0; q < QPL; ++q) {
        // ||q||^2 = 0.25 * (qx2^2 + qy2^2 + qz2^2)
        float nq2 = fmaf(qz2[q], qz2[q],
                    fmaf(qy2[q], qy2[q], qx2[q] * qx2[q])) * 0.25f;
        float v = mn[q] + nq2;
        atomicMin(&wsd[qgbase + q * BLK + tid], f2ord(v));
    }
}

__global__ __launch_bounds__(256) void reduce_sums(
    const unsigned int* __restrict__ ws, float* __restrict__ out) {
    float s1 = 0.0f, s2 = 0.0f;
    for (int i = blockIdx.x * 256 + threadIdx.x; i < WS_WORDS;
         i += gridDim.x * 256) {
        float v = ord2f(ws[i]);
        if (i < NQD1) s1 += v; else s2 += v;
    }
#pragma unroll
    for (int off = 32; off > 0; off >>= 1) {
        s1 += __shfl_xor(s1, off, 64);
        s2 += __shfl_xor(s2, off, 64);
    }
    __shared__ float a1[4], a2[4];
    int w = threadIdx.x >> 6;
    if ((threadIdx.x & 63) == 0) { a1[w] = s1; a2[w] = s2; }
    __syncthreads();
    if (threadIdx.x == 0) {
        atomicAdd(&out[2], a1[0] + a1[1] + a1[2] + a1[3]);
        atomicAdd(&out[3], a2[0] + a2[1] + a2[2] + a2[3]);
    }
}

// ---------------- fallback path (no / small d_ws) ----------------

__global__ void init_out(float* out) {
    if (threadIdx.x == 0) { out[2] = 0.0f; out[3] = 0.0f; }
}

__device__ __forceinline__ void scan_refs(const float* __restrict__ r, int cnt,
                                          float px, float py, float pz,
                                          float& minv) {
    for (int m = 0; m < cnt; m += 8) {
#pragma unroll
        for (int u = 0; u < 8; ++u) {
            float mx = r[(m + u) * 3 + 0];
            float my = r[(m + u) * 3 + 1];
            float mz = r[(m + u) * 3 + 2];
            float dx = px - mx, dy = py - my, dz = pz - mz;
            float d = fmaf(dz, dz, fmaf(dy, dy, dx * dx));
            minv = fminf(minv, d);
        }
    }
}

__global__ __launch_bounds__(64) void chamfer_sum(
    const float* __restrict__ qa, int na_, const float* __restrict__ qb, int nb_,
    const float* __restrict__ ra, int ma, const float* __restrict__ rb, int mb,
    float* __restrict__ accum) {
    const int b = blockIdx.y;
    const int n = blockIdx.x * 64 + threadIdx.x;
    float px, py, pz;
    if (n < na_) {
        const float* p = qa + ((size_t)b * na_ + n) * 3;
        px = p[0]; py = p[1]; pz = p[2];
    } else {
        const float* p = qb + ((size_t)b * nb_ + (n - na_)) * 3;
        px = p[0]; py = p[1]; pz = p[2];
    }
    float minv = 3.0e38f;
    scan_refs(ra + (size_t)b * ma * 3, ma, px, py, pz, minv);
    if (mb > 0) scan_refs(rb + (size_t)b * mb * 3, mb, px, py, pz, minv);
    float s = minv;
#pragma unroll
    for (int off = 32; off > 0; off >>= 1) s += __shfl_xor(s, off, 64);
    if (threadIdx.x == 0) atomicAdd(accum, s);
}

// ---------------- finalize (shared by both paths) ----------------

__global__ __launch_bounds__(64) void finalize_kernel(
    const float* __restrict__ logits, float* __restrict__ out) {
    const int lane = threadIdx.x;
    float pose_part = 0.0f;
    if (lane < BATCH) {
        const float* L = logits + lane * NHYP;
        float mx = L[0];
#pragma unroll 8
        for (int j = 1; j < NHYP; ++j) mx = fmaxf(mx, L[j]);
        float s = 0.0f;
#pragma unroll 8
        for (int j = 0; j < NHYP; ++j) s += expf(L[j] - mx);
        pose_part = L[0] - (mx + logf(s));  // log_prob[b, 0]
    }
#pragma unroll
    for (int off = 8; off > 0; off >>= 1) pose_part += __shfl_xor(pose_part, off, 64);
    if (lane == 0) {
        float mean1 = out[2] / (float)NQD1;
        float mean2 = out[3] / (float)NQD2;
        float shape_loss = mean1 + mean2;
        float pose_loss = -pose_part / (float)BATCH;
        float loss = 0.4f * pose_loss + 0.6f * shape_loss;
        out[0] = loss;
        out[1] = pose_loss;
        out[2] = shape_loss;
        out[3] = shape_loss;  // sdf_loss
        out[4] = shape_loss;  // caption_loss
    }
}

extern "C" void kernel_launch(void* const* d_in, const int* in_sizes, int n_in,
                              void* d_out, int out_size, void* d_ws, size_t ws_size,
                              hipStream_t stream) {
    const float* shape_query = (const float*)d_in[0];  // (16,4096,3)
    const float* logits      = (const float*)d_in[1];  // (16,64)
    const float* prior       = (const float*)d_in[5];  // (16,1024,3)
    const float* model       = (const float*)d_in[6];  // (16,4096,3)
    float* out = (float*)d_out;

    if (ws_size >= WS_BYTES) {
        unsigned int* ws = (unsigned int*)d_ws;
        hipLaunchKernelGGL(init_ws, dim3((WS_WORDS + 255) / 256), dim3(256), 0,
                           stream, ws, out);
        const int nblocks = BATCH * QT1 * SLICES + BATCH * QT2 * SLICES;  // 2304
        hipLaunchKernelGGL(chamfer_main, dim3(nblocks), dim3(BLK), 0, stream,
                           shape_query, prior, model, ws);
        hipLaunchKernelGGL(reduce_sums, dim3(128), dim3(256), 0, stream, ws, out);
    } else {
        hipLaunchKernelGGL(init_out, dim3(1), dim3(64), 0, stream, out);
        hipLaunchKernelGGL(chamfer_sum,
                           dim3(NREC / 64, BATCH), dim3(64), 0, stream,
                           shape_query, NQ, prior, NPRIOR,
                           model, NMODEL, (const float*)nullptr, 0, out + 2);
        hipLaunchKernelGGL(chamfer_sum,
                           dim3(NMODEL / 64, BATCH), dim3(64), 0, stream,
                           model, NMODEL, (const float*)nullptr, 0,
                           shape_query, NQ, prior, NPRIOR, out + 3);
    }
    hipLaunchKernelGGL(finalize_kernel, dim3(1), dim3(64), 0, stream, logits, out);
}